// Round 2
// baseline (872.800 us; speedup 1.0000x reference)
//
#include <hip/hip_runtime.h>
#include <hip/hip_bf16.h>

__device__ __forceinline__ float wsum(float v){
  #pragma unroll
  for (int m = 32; m >= 1; m >>= 1) v += __shfl_xor(v, m);
  return v;
}
__device__ __forceinline__ float wmax(float v){
  #pragma unroll
  for (int m = 32; m >= 1; m >>= 1) v = fmaxf(v, __shfl_xor(v, m));
  return v;
}
__device__ __forceinline__ float lrelu(float a){ return a > 0.f ? a : 0.2f * a; }

// we = We @ a_edge (per layer), zero-padded to 64
__global__ void k_we(const float* __restrict__ We1, const float* __restrict__ ae1,
                     const float* __restrict__ We2, const float* __restrict__ ae2,
                     float* __restrict__ we1, float* __restrict__ we2, int ED, int H) {
  int j = threadIdx.x;  // 64 threads
  float s1 = 0.f, s2 = 0.f;
  if (j < ED) {
    for (int h = 0; h < H; ++h) {
      s1 += We1[j * H + h] * ae1[h];
      s2 += We2[j * H + h] * ae2[h];
    }
  }
  we1[j] = s1; we2[j] = s2;
}

__global__ void k_count(const int* __restrict__ dst, int* __restrict__ degi, int E) {
  int e = blockIdx.x * blockDim.x + threadIdx.x;
  if (e < E) atomicAdd(degi + dst[e], 1);
}

// single-block exclusive scan of degi -> rowptr
__global__ void k_scan(const int* __restrict__ degi, int* __restrict__ rowptr, int N, int E) {
  __shared__ int part[1024];
  int t = threadIdx.x;
  int chunk = (N + 1023) >> 10;
  int lo = t * chunk, hi = min(lo + chunk, N);
  int s = 0;
  for (int i = lo; i < hi; ++i) s += degi[i];
  part[t] = s;
  __syncthreads();
  for (int off = 1; off < 1024; off <<= 1) {
    int v = (t >= off) ? part[t - off] : 0;
    __syncthreads();
    part[t] += v;
    __syncthreads();
  }
  int base = (t == 0) ? 0 : part[t - 1];
  for (int i = lo; i < hi; ++i) { rowptr[i] = base; base += degi[i]; }
  if (t == 0) rowptr[N] = E;
}

// per-edge: e-dot for both layers, CSR fill, esum atomics
__global__ void k_fill(const int* __restrict__ src, const int* __restrict__ dst,
                       const float* __restrict__ ef,
                       const float* __restrict__ we1, const float* __restrict__ we2,
                       const int* __restrict__ rowptr, int* __restrict__ cursor,
                       int* __restrict__ csr_src, float* __restrict__ csr_e1, float* __restrict__ csr_e2,
                       float* __restrict__ esum1, float* __restrict__ esum2, int E, int ED) {
  __shared__ float w1[64], w2[64];
  if (threadIdx.x < 64) { w1[threadIdx.x] = we1[threadIdx.x]; w2[threadIdx.x] = we2[threadIdx.x]; }
  __syncthreads();
  int e = blockIdx.x * blockDim.x + threadIdx.x;
  if (e >= E) return;
  const float4* row = reinterpret_cast<const float4*>(ef + (size_t)e * ED);
  float d1 = 0.f, d2 = 0.f;
  #pragma unroll
  for (int i = 0; i < 15; ++i) {   // ED=60 -> 15 float4
    float4 f = row[i];
    d1 += f.x * w1[4*i] + f.y * w1[4*i+1] + f.z * w1[4*i+2] + f.w * w1[4*i+3];
    d2 += f.x * w2[4*i] + f.y * w2[4*i+1] + f.z * w2[4*i+2] + f.w * w2[4*i+3];
  }
  int d = dst[e];
  int slot = rowptr[d] + atomicAdd(cursor + d, 1);
  csr_src[slot] = src[e];
  csr_e1[slot] = d1;
  csr_e2[slot] = d2;
  atomicAdd(esum1 + d, d1);
  atomicAdd(esum2 + d, d2);
}

// fp32 tiled GEMM: C[M,128] = A[M,K] @ B[K,128]; block: 32 rows x 128 cols, 4x4 per thread
template <int K>
__global__ __launch_bounds__(256) void k_gemm(const float* __restrict__ A, const float* __restrict__ B,
                                              float* __restrict__ C, int M) {
  __shared__ float As[32][36];   // +4 pad: conflict-free row reads
  __shared__ float Bs[32][128];
  int tid = threadIdx.x;
  int m0 = blockIdx.x * 32;
  int tr = tid >> 5;        // 0..7  (4-row group)
  int tc = tid & 31;        // 0..31 (4-col group)
  int la_m = tid >> 3;      // 0..31
  int la_k = (tid & 7) * 4; // 0..28
  float acc[4][4] = {};
  for (int k0 = 0; k0 < K; k0 += 32) {
    {
      int m = m0 + la_m;
      float4 av = make_float4(0.f, 0.f, 0.f, 0.f);
      if (m < M) av = *reinterpret_cast<const float4*>(A + (size_t)m * K + k0 + la_k);
      *reinterpret_cast<float4*>(&As[la_m][la_k]) = av;
    }
    #pragma unroll
    for (int it = 0; it < 4; ++it) {
      int f = it * 256 + tid;              // 0..1023 float4s of the 32x128 chunk
      int bk = f >> 5, bn = (f & 31) * 4;
      float4 bv = *reinterpret_cast<const float4*>(B + (size_t)(k0 + bk) * 128 + bn);
      *reinterpret_cast<float4*>(&Bs[bk][bn]) = bv;
    }
    __syncthreads();
    #pragma unroll
    for (int k = 0; k < 32; ++k) {
      float4 b4 = *reinterpret_cast<const float4*>(&Bs[k][tc * 4]);
      float a0 = As[tr*4+0][k], a1 = As[tr*4+1][k], a2 = As[tr*4+2][k], a3 = As[tr*4+3][k];
      acc[0][0] += a0*b4.x; acc[0][1] += a0*b4.y; acc[0][2] += a0*b4.z; acc[0][3] += a0*b4.w;
      acc[1][0] += a1*b4.x; acc[1][1] += a1*b4.y; acc[1][2] += a1*b4.z; acc[1][3] += a1*b4.w;
      acc[2][0] += a2*b4.x; acc[2][1] += a2*b4.y; acc[2][2] += a2*b4.z; acc[2][3] += a2*b4.w;
      acc[3][0] += a3*b4.x; acc[3][1] += a3*b4.y; acc[3][2] += a3*b4.z; acc[3][3] += a3*b4.w;
    }
    __syncthreads();
  }
  #pragma unroll
  for (int r = 0; r < 4; ++r) {
    int m = m0 + tr * 4 + r;
    if (m < M) {
      float4 ov = make_float4(acc[r][0], acc[r][1], acc[r][2], acc[r][3]);
      *reinterpret_cast<float4*>(C + (size_t)m * 128 + tc * 4) = ov;
    }
  }
}

// alpha_s[i] = h[i,:] . a_src ; alpha_d[i] = h[i,:] . a_dst  (one wave per node)
__global__ void k_alpha(const float* __restrict__ h,
                        const float* __restrict__ a_src, const float* __restrict__ a_dst,
                        float* __restrict__ as_, float* __restrict__ ad_, int N) {
  int wave = (blockIdx.x * blockDim.x + threadIdx.x) >> 6;
  int lane = threadIdx.x & 63;
  if (wave >= N) return;
  const float2* hp = reinterpret_cast<const float2*>(h) + (size_t)wave * 64;
  float2 hv = hp[lane];
  float2 sv = reinterpret_cast<const float2*>(a_src)[lane];
  float2 dv = reinterpret_cast<const float2*>(a_dst)[lane];
  float ps = hv.x * sv.x + hv.y * sv.y;
  float pd = hv.x * dv.x + hv.y * dv.y;
  ps = wsum(ps);
  pd = wsum(pd);
  if (lane == 0) { as_[wave] = ps; ad_[wave] = pd; }
}

// segment softmax + aggregation, one wave per dst node; lane owns channels {2*lane, 2*lane+1}
__global__ void k_agg(const int* __restrict__ rowptr, const int* __restrict__ csr_src,
                      const float* __restrict__ csr_e, const float* __restrict__ esum,
                      const float* __restrict__ as_, const float* __restrict__ ad_,
                      const float* __restrict__ h, const float* __restrict__ bias,
                      float* __restrict__ out, int N, int do_relu) {
  int i = (blockIdx.x * blockDim.x + threadIdx.x) >> 6;
  int lane = threadIdx.x & 63;
  if (i >= N) return;
  int start = rowptr[i], end = rowptr[i + 1];
  int cnt = end - start;
  float adi = ad_[i], asi = as_[i];
  float degf = fmaxf((float)cnt, 1.0f);
  float a_self = lrelu(asi + adi + esum[i] / degf);
  // pass 1: exact segment max (incl. self loop)
  float M = a_self;
  for (int idx = start + lane; idx < end; idx += 64) {
    float a = lrelu(as_[csr_src[idx]] + adi + csr_e[idx]);
    M = fmaxf(M, a);
  }
  M = wmax(M);
  // pass 2: exp weights + channel accumulation
  const float2* hp = reinterpret_cast<const float2*>(h);
  float acc0 = 0.f, acc1 = 0.f, S = 0.f;
  for (int chunk = start; chunk < end; chunk += 64) {
    int idx = chunk + lane;
    int sv = 0;
    float w = 0.f;
    if (idx < end) {
      sv = csr_src[idx];
      float a = lrelu(as_[sv] + adi + csr_e[idx]);
      w = __expf(a - M);
      S += w;
    }
    int mcnt = min(64, end - chunk);
    for (int j = 0; j < mcnt; ++j) {
      float wj = __shfl(w, j);
      int sj = __shfl(sv, j);
      float2 hv = hp[(size_t)sj * 64 + lane];
      acc0 += wj * hv.x;
      acc1 += wj * hv.y;
    }
  }
  float w_self = __expf(a_self - M);
  S = wsum(S) + w_self;
  float2 hv = hp[(size_t)i * 64 + lane];
  acc0 += w_self * hv.x;
  acc1 += w_self * hv.y;
  float inv = 1.0f / S;
  float2 bv = reinterpret_cast<const float2*>(bias)[lane];
  float o0 = acc0 * inv + bv.x;
  float o1 = acc1 * inv + bv.y;
  if (do_relu) { o0 = fmaxf(o0, 0.f); o1 = fmaxf(o1, 0.f); }
  float2 ov; ov.x = o0; ov.y = o1;
  reinterpret_cast<float2*>(out)[(size_t)i * 64 + lane] = ov;
}

// out[k] = z[src[k]].z[dst[k]] + z[src[k+half]].z[dst[k+half]]  (one wave per k)
__global__ void k_decode(const int* __restrict__ src, const int* __restrict__ dst,
                         const float* __restrict__ z, float* __restrict__ out, int half) {
  int k = (blockIdx.x * blockDim.x + threadIdx.x) >> 6;
  int lane = threadIdx.x & 63;
  if (k >= half) return;
  int s1 = src[k], d1 = dst[k], s2 = src[k + half], d2 = dst[k + half];
  const float2* zp = reinterpret_cast<const float2*>(z);
  float2 a = zp[(size_t)s1 * 64 + lane];
  float2 b = zp[(size_t)d1 * 64 + lane];
  float2 c = zp[(size_t)s2 * 64 + lane];
  float2 d = zp[(size_t)d2 * 64 + lane];
  float p = a.x * b.x + a.y * b.y + c.x * d.x + c.y * d.y;
  p = wsum(p);
  if (lane == 0) out[k] = p;
}

extern "C" void kernel_launch(void* const* d_in, const int* in_sizes, int n_in,
                              void* d_out, int out_size, void* d_ws, size_t ws_size,
                              hipStream_t stream) {
  const int H = 128;
  const int N = in_sizes[0] / 256;        // 50000
  const int E = in_sizes[1] / 2;          // 800000
  const int ED = in_sizes[2] / E;         // 60
  const int half = E / 2;

  const float* x   = (const float*)d_in[0];
  const int* eidx  = (const int*)d_in[1];
  const float* ef  = (const float*)d_in[2];
  const float* W1  = (const float*)d_in[4];
  const float* as1 = (const float*)d_in[5];
  const float* ad1 = (const float*)d_in[6];
  const float* We1 = (const float*)d_in[7];
  const float* ae1 = (const float*)d_in[8];
  const float* b1  = (const float*)d_in[9];
  const float* W2  = (const float*)d_in[10];
  const float* as2 = (const float*)d_in[11];
  const float* ad2 = (const float*)d_in[12];
  const float* We2 = (const float*)d_in[13];
  const float* ae2 = (const float*)d_in[14];
  const float* b2  = (const float*)d_in[15];

  const int* src = eidx;
  const int* dst = eidx + E;

  size_t off = 0;
  auto alloc = [&](size_t bytes) -> void* {
    void* p = (char*)d_ws + off;
    off += (bytes + 255) & ~(size_t)255;
    return p;
  };
  float* we1   = (float*)alloc(64 * 4);
  float* we2   = (float*)alloc(64 * 4);
  int*   degi  = (int*)alloc((size_t)N * 4);
  int*   cursor= (int*)alloc((size_t)N * 4);
  float* esum1 = (float*)alloc((size_t)N * 4);
  float* esum2 = (float*)alloc((size_t)N * 4);
  int*   rowptr= (int*)alloc((size_t)(N + 1) * 4);
  float* alps  = (float*)alloc((size_t)N * 4);
  float* alpd  = (float*)alloc((size_t)N * 4);
  int*   csr_src = (int*)alloc((size_t)E * 4);
  float* csr_e1  = (float*)alloc((size_t)E * 4);
  float* csr_e2  = (float*)alloc((size_t)E * 4);
  float* hA = (float*)alloc((size_t)N * H * 4);
  float* hB = (float*)alloc((size_t)N * H * 4);

  hipMemsetAsync(degi,   0, (size_t)N * 4, stream);
  hipMemsetAsync(cursor, 0, (size_t)N * 4, stream);
  hipMemsetAsync(esum1,  0, (size_t)N * 4, stream);
  hipMemsetAsync(esum2,  0, (size_t)N * 4, stream);

  k_we<<<1, 64, 0, stream>>>(We1, ae1, We2, ae2, we1, we2, ED, H);
  k_count<<<(E + 255) / 256, 256, 0, stream>>>(dst, degi, E);
  k_scan<<<1, 1024, 0, stream>>>(degi, rowptr, N, E);
  k_fill<<<(E + 255) / 256, 256, 0, stream>>>(src, dst, ef, we1, we2, rowptr, cursor,
                                              csr_src, csr_e1, csr_e2, esum1, esum2, E, ED);

  int gblocks = (N + 31) / 32;
  // ---- layer 1 ----
  k_gemm<256><<<gblocks, 256, 0, stream>>>(x, W1, hA, N);
  k_alpha<<<(N + 3) / 4, 256, 0, stream>>>(hA, as1, ad1, alps, alpd, N);
  k_agg<<<(N + 3) / 4, 256, 0, stream>>>(rowptr, csr_src, csr_e1, esum1, alps, alpd,
                                         hA, b1, hB, N, 1);
  // ---- layer 2 ----
  k_gemm<128><<<gblocks, 256, 0, stream>>>(hB, W2, hA, N);
  k_alpha<<<(N + 3) / 4, 256, 0, stream>>>(hA, as2, ad2, alps, alpd, N);
  k_agg<<<(N + 3) / 4, 256, 0, stream>>>(rowptr, csr_src, csr_e2, esum2, alps, alpd,
                                         hA, b2, hB, N, 0);
  // ---- decode ----
  k_decode<<<(half + 3) / 4, 256, 0, stream>>>(src, dst, hB, (float*)d_out, half);
}

// Round 3
// 799.016 us; speedup vs baseline: 1.0923x; 1.0923x over previous
//
#include <hip/hip_runtime.h>
#include <hip/hip_bf16.h>

__device__ __forceinline__ float wsum(float v){
  #pragma unroll
  for (int m = 32; m >= 1; m >>= 1) v += __shfl_xor(v, m);
  return v;
}
__device__ __forceinline__ float lrelu(float a){ return a > 0.f ? a : 0.2f * a; }

// we = We @ a_edge (per layer), zero-padded to 64
__global__ void k_we(const float* __restrict__ We1, const float* __restrict__ ae1,
                     const float* __restrict__ We2, const float* __restrict__ ae2,
                     float* __restrict__ we1, float* __restrict__ we2, int ED, int H) {
  int j = threadIdx.x;  // 64 threads
  float s1 = 0.f, s2 = 0.f;
  if (j < ED) {
    const float4* r1 = reinterpret_cast<const float4*>(We1 + j * H);
    const float4* r2 = reinterpret_cast<const float4*>(We2 + j * H);
    const float4* a1 = reinterpret_cast<const float4*>(ae1);
    const float4* a2 = reinterpret_cast<const float4*>(ae2);
    for (int i = 0; i < H / 4; ++i) {
      float4 x1 = r1[i], y1 = a1[i];
      float4 x2 = r2[i], y2 = a2[i];
      s1 += x1.x*y1.x + x1.y*y1.y + x1.z*y1.z + x1.w*y1.w;
      s2 += x2.x*y2.x + x2.y*y2.y + x2.z*y2.z + x2.w*y2.w;
    }
  }
  we1[j] = s1; we2[j] = s2;
}

__global__ void k_count(const int* __restrict__ dst, int* __restrict__ degi, int E) {
  int e = blockIdx.x * blockDim.x + threadIdx.x;
  if (e < E) atomicAdd(degi + dst[e], 1);
}

// single-block exclusive scan of degi -> rowptr
__global__ void k_scan(const int* __restrict__ degi, int* __restrict__ rowptr, int N, int E) {
  __shared__ int part[1024];
  int t = threadIdx.x;
  int chunk = (N + 1023) >> 10;
  int lo = t * chunk, hi = min(lo + chunk, N);
  int s = 0;
  for (int i = lo; i < hi; ++i) s += degi[i];
  part[t] = s;
  __syncthreads();
  for (int off = 1; off < 1024; off <<= 1) {
    int v = (t >= off) ? part[t - off] : 0;
    __syncthreads();
    part[t] += v;
    __syncthreads();
  }
  int base = (t == 0) ? 0 : part[t - 1];
  for (int i = lo; i < hi; ++i) { rowptr[i] = base; base += degi[i]; }
  if (t == 0) rowptr[N] = E;
}

// 4 lanes per edge: e-dots for both layers, single packed float4 CSR scatter
__global__ __launch_bounds__(256) void k_fill(const int* __restrict__ src, const int* __restrict__ dst,
                       const float* __restrict__ ef,
                       const float* __restrict__ we1, const float* __restrict__ we2,
                       const int* __restrict__ rowptr, int* __restrict__ cursor,
                       float4* __restrict__ csr, int E) {
  __shared__ float w1[64], w2[64];
  int t = threadIdx.x;
  if (t < 64) { w1[t] = we1[t]; w2[t] = we2[t]; }
  __syncthreads();
  int gid = blockIdx.x * 256 + t;
  int e = gid >> 2;
  int sub = gid & 3;
  if (e >= E) return;
  const float4* row = reinterpret_cast<const float4*>(ef + (size_t)e * 60);
  float d1 = 0.f, d2 = 0.f;
  #pragma unroll
  for (int i = sub; i < 15; i += 4) {   // 15 float4s per 60-float row
    float4 f = row[i];
    d1 += f.x*w1[4*i] + f.y*w1[4*i+1] + f.z*w1[4*i+2] + f.w*w1[4*i+3];
    d2 += f.x*w2[4*i] + f.y*w2[4*i+1] + f.z*w2[4*i+2] + f.w*w2[4*i+3];
  }
  d1 += __shfl_xor(d1, 1); d1 += __shfl_xor(d1, 2);
  d2 += __shfl_xor(d2, 1); d2 += __shfl_xor(d2, 2);
  if (sub == 0) {
    int d = dst[e];
    int slot = rowptr[d] + atomicAdd(cursor + d, 1);
    float4 v;
    v.x = __int_as_float(src[e]); v.y = d1; v.z = d2; v.w = 0.f;
    csr[slot] = v;
  }
}

// fp32 tiled GEMM: C[M,128] = A[M,K] @ B[K,128]; block 32x128, 4x4/thread, A-tile transposed in LDS
template <int K>
__global__ __launch_bounds__(256) void k_gemm(const float* __restrict__ A, const float* __restrict__ B,
                                              float* __restrict__ C, int M) {
  __shared__ float AsT[32][36];   // [k][m], +4 pad
  __shared__ float Bs[32][128];
  int tid = threadIdx.x;
  int m0 = blockIdx.x * 32;
  int tr = tid >> 5;        // 0..7
  int tc = tid & 31;        // 0..31
  int la_m = tid >> 3;      // 0..31
  int la_k = (tid & 7) * 4; // 0..28
  float acc[4][4] = {};
  for (int k0 = 0; k0 < K; k0 += 32) {
    {
      int m = m0 + la_m;
      float4 av = make_float4(0.f, 0.f, 0.f, 0.f);
      if (m < M) av = *reinterpret_cast<const float4*>(A + (size_t)m * K + k0 + la_k);
      AsT[la_k + 0][la_m] = av.x;
      AsT[la_k + 1][la_m] = av.y;
      AsT[la_k + 2][la_m] = av.z;
      AsT[la_k + 3][la_m] = av.w;
    }
    #pragma unroll
    for (int it = 0; it < 4; ++it) {
      int f = it * 256 + tid;
      int bk = f >> 5, bn = (f & 31) * 4;
      float4 bv = *reinterpret_cast<const float4*>(B + (size_t)(k0 + bk) * 128 + bn);
      *reinterpret_cast<float4*>(&Bs[bk][bn]) = bv;
    }
    __syncthreads();
    #pragma unroll
    for (int k = 0; k < 32; ++k) {
      float4 b4 = *reinterpret_cast<const float4*>(&Bs[k][tc * 4]);
      float4 a4 = *reinterpret_cast<const float4*>(&AsT[k][tr * 4]);
      acc[0][0] += a4.x*b4.x; acc[0][1] += a4.x*b4.y; acc[0][2] += a4.x*b4.z; acc[0][3] += a4.x*b4.w;
      acc[1][0] += a4.y*b4.x; acc[1][1] += a4.y*b4.y; acc[1][2] += a4.y*b4.z; acc[1][3] += a4.y*b4.w;
      acc[2][0] += a4.z*b4.x; acc[2][1] += a4.z*b4.y; acc[2][2] += a4.z*b4.z; acc[2][3] += a4.z*b4.w;
      acc[3][0] += a4.w*b4.x; acc[3][1] += a4.w*b4.y; acc[3][2] += a4.w*b4.z; acc[3][3] += a4.w*b4.w;
    }
    __syncthreads();
  }
  #pragma unroll
  for (int r = 0; r < 4; ++r) {
    int m = m0 + tr * 4 + r;
    if (m < M) {
      float4 ov = make_float4(acc[r][0], acc[r][1], acc[r][2], acc[r][3]);
      *reinterpret_cast<float4*>(C + (size_t)m * 128 + tc * 4) = ov;
    }
  }
}

// alpha_s[i] = h[i,:].a_src ; alpha_d[i] = h[i,:].a_dst  (one wave per node)
__global__ void k_alpha(const float* __restrict__ h,
                        const float* __restrict__ a_src, const float* __restrict__ a_dst,
                        float* __restrict__ as_, float* __restrict__ ad_, int N) {
  int wave = (blockIdx.x * blockDim.x + threadIdx.x) >> 6;
  int lane = threadIdx.x & 63;
  if (wave >= N) return;
  const float2* hp = reinterpret_cast<const float2*>(h) + (size_t)wave * 64;
  float2 hv = hp[lane];
  float2 sv = reinterpret_cast<const float2*>(a_src)[lane];
  float2 dv = reinterpret_cast<const float2*>(a_dst)[lane];
  float ps = hv.x * sv.x + hv.y * sv.y;
  float pd = hv.x * dv.x + hv.y * dv.y;
  ps = wsum(ps);
  pd = wsum(pd);
  if (lane == 0) { as_[wave] = ps; ad_[wave] = pd; }
}

// single-pass online-softmax aggregation; wave per node, half-wave per edge stream,
// lane owns 4 channels (float4). esum computed inline (self-loop edge term).
__global__ __launch_bounds__(256) void k_agg(const int* __restrict__ rowptr, const float4* __restrict__ csr,
                      const float* __restrict__ as_, const float* __restrict__ ad_,
                      const float* __restrict__ h, const float* __restrict__ bias,
                      float* __restrict__ out, int N, int use2, int do_relu) {
  int i = (blockIdx.x * blockDim.x + threadIdx.x) >> 6;
  int lane = threadIdx.x & 63;
  if (i >= N) return;
  int q = lane & 31;
  int half = lane >> 5;
  int start = rowptr[i], end = rowptr[i + 1];
  int cnt = end - start;
  float adi = ad_[i], asi = as_[i];
  const float4* h4 = reinterpret_cast<const float4*>(h);
  float m = -3.0e38f, s = 0.f, esum = 0.f;
  float4 acc = make_float4(0.f, 0.f, 0.f, 0.f);
  for (int idx = start + half; idx < end; idx += 2) {
    float4 ce = csr[idx];                       // broadcast within half-wave
    int sv = __float_as_int(ce.x);
    float e = use2 ? ce.z : ce.y;
    float a = lrelu(as_[sv] + adi + e);
    esum += e;
    if (a > m) {
      float r = __expf(m - a);                  // first hit: exp(-huge)=0
      s *= r; acc.x *= r; acc.y *= r; acc.z *= r; acc.w *= r;
      m = a;
    }
    float w = __expf(a - m);
    s += w;
    float4 hv = h4[(size_t)sv * 32 + q];
    acc.x += w * hv.x; acc.y += w * hv.y; acc.z += w * hv.z; acc.w += w * hv.w;
  }
  // merge halves (online-softmax merge; empty half has m=-3e38,s=0 -> exp factor 0 or exp(0)=1, safe)
  float m_o = __shfl_xor(m, 32);
  float s_o = __shfl_xor(s, 32);
  float e_o = __shfl_xor(esum, 32);
  float4 ao;
  ao.x = __shfl_xor(acc.x, 32); ao.y = __shfl_xor(acc.y, 32);
  ao.z = __shfl_xor(acc.z, 32); ao.w = __shfl_xor(acc.w, 32);
  float Mn = fmaxf(m, m_o);
  float f  = __expf(m - Mn), fo = __expf(m_o - Mn);
  s = s * f + s_o * fo;
  acc.x = acc.x * f + ao.x * fo; acc.y = acc.y * f + ao.y * fo;
  acc.z = acc.z * f + ao.z * fo; acc.w = acc.w * f + ao.w * fo;
  float esum_t = esum + e_o;
  // merge self-loop
  float a_self = lrelu(asi + adi + esum_t / fmaxf((float)cnt, 1.f));
  float M2 = fmaxf(Mn, a_self);
  float g = __expf(Mn - M2);
  float w_self = __expf(a_self - M2);
  s = s * g + w_self;
  float4 hs = h4[(size_t)i * 32 + q];
  acc.x = acc.x * g + w_self * hs.x; acc.y = acc.y * g + w_self * hs.y;
  acc.z = acc.z * g + w_self * hs.z; acc.w = acc.w * g + w_self * hs.w;
  float inv = 1.0f / s;
  float4 bv = reinterpret_cast<const float4*>(bias)[q];
  float4 o;
  o.x = acc.x * inv + bv.x; o.y = acc.y * inv + bv.y;
  o.z = acc.z * inv + bv.z; o.w = acc.w * inv + bv.w;
  if (do_relu) {
    o.x = fmaxf(o.x, 0.f); o.y = fmaxf(o.y, 0.f);
    o.z = fmaxf(o.z, 0.f); o.w = fmaxf(o.w, 0.f);
  }
  if (half == 0)
    reinterpret_cast<float4*>(out)[(size_t)i * 32 + q] = o;
}

// out[k] = z[src[k]].z[dst[k]] + z[src[k+half]].z[dst[k+half]]; half-wave per pair, float4/lane
__global__ void k_decode(const int* __restrict__ src, const int* __restrict__ dst,
                         const float* __restrict__ z, float* __restrict__ out, int halfE) {
  int k = (blockIdx.x * blockDim.x + threadIdx.x) >> 6;
  int lane = threadIdx.x & 63;
  if (k >= halfE) return;
  int hh = lane >> 5, q = lane & 31;
  int e = k + hh * halfE;
  int sv = src[e], dv = dst[e];               // broadcast within half-wave
  const float4* z4 = reinterpret_cast<const float4*>(z);
  float4 a = z4[(size_t)sv * 32 + q];
  float4 b = z4[(size_t)dv * 32 + q];
  float p = a.x*b.x + a.y*b.y + a.z*b.z + a.w*b.w;
  p = wsum(p);                                 // sums across both halves
  if (lane == 0) out[k] = p;
}

extern "C" void kernel_launch(void* const* d_in, const int* in_sizes, int n_in,
                              void* d_out, int out_size, void* d_ws, size_t ws_size,
                              hipStream_t stream) {
  const int H = 128;
  const int N = in_sizes[0] / 256;        // 50000
  const int E = in_sizes[1] / 2;          // 800000
  const int half = E / 2;

  const float* x   = (const float*)d_in[0];
  const int* eidx  = (const int*)d_in[1];
  const float* ef  = (const float*)d_in[2];
  const float* W1  = (const float*)d_in[4];
  const float* as1 = (const float*)d_in[5];
  const float* ad1 = (const float*)d_in[6];
  const float* We1 = (const float*)d_in[7];
  const float* ae1 = (const float*)d_in[8];
  const float* b1  = (const float*)d_in[9];
  const float* W2  = (const float*)d_in[10];
  const float* as2 = (const float*)d_in[11];
  const float* ad2 = (const float*)d_in[12];
  const float* We2 = (const float*)d_in[13];
  const float* ae2 = (const float*)d_in[14];
  const float* b2  = (const float*)d_in[15];

  const int* src = eidx;
  const int* dst = eidx + E;

  size_t off = 0;
  auto alloc = [&](size_t bytes) -> void* {
    void* p = (char*)d_ws + off;
    off += (bytes + 255) & ~(size_t)255;
    return p;
  };
  float*  we1    = (float*)alloc(64 * 4);
  float*  we2    = (float*)alloc(64 * 4);
  int*    degi   = (int*)alloc((size_t)N * 4);
  int*    cursor = (int*)alloc((size_t)N * 4);
  int*    rowptr = (int*)alloc((size_t)(N + 1) * 4);
  float*  alps   = (float*)alloc((size_t)N * 4);
  float*  alpd   = (float*)alloc((size_t)N * 4);
  float4* csr    = (float4*)alloc((size_t)E * 16);
  float*  hA     = (float*)alloc((size_t)N * H * 4);
  float*  hB     = (float*)alloc((size_t)N * H * 4);

  hipMemsetAsync(degi,   0, (size_t)N * 4, stream);
  hipMemsetAsync(cursor, 0, (size_t)N * 4, stream);

  k_we<<<1, 64, 0, stream>>>(We1, ae1, We2, ae2, we1, we2, 60, H);
  k_count<<<(E + 255) / 256, 256, 0, stream>>>(dst, degi, E);
  k_scan<<<1, 1024, 0, stream>>>(degi, rowptr, N, E);
  k_fill<<<(E * 4 + 255) / 256, 256, 0, stream>>>(src, dst, ef, we1, we2, rowptr, cursor, csr, E);

  int gblocks = (N + 31) / 32;
  // ---- layer 1 ----
  k_gemm<256><<<gblocks, 256, 0, stream>>>(x, W1, hA, N);
  k_alpha<<<(N + 3) / 4, 256, 0, stream>>>(hA, as1, ad1, alps, alpd, N);
  k_agg<<<(N + 3) / 4, 256, 0, stream>>>(rowptr, csr, alps, alpd, hA, b1, hB, N, 0, 1);
  // ---- layer 2 ----
  k_gemm<128><<<gblocks, 256, 0, stream>>>(hB, W2, hA, N);
  k_alpha<<<(N + 3) / 4, 256, 0, stream>>>(hA, as2, ad2, alps, alpd, N);
  k_agg<<<(N + 3) / 4, 256, 0, stream>>>(rowptr, csr, alps, alpd, hA, b2, hB, N, 1, 0);
  // ---- decode ----
  k_decode<<<(half + 3) / 4, 256, 0, stream>>>(src, dst, hB, (float*)d_out, half);
}

// Round 4
// 753.030 us; speedup vs baseline: 1.1591x; 1.0611x over previous
//
#include <hip/hip_runtime.h>
#include <hip/hip_bf16.h>

typedef __attribute__((ext_vector_type(8))) short short8;
typedef __attribute__((ext_vector_type(4))) float floatx4;

__device__ __forceinline__ float wsum(float v){
  #pragma unroll
  for (int m = 32; m >= 1; m >>= 1) v += __shfl_xor(v, m);
  return v;
}
__device__ __forceinline__ float lrelu(float a){ return a > 0.f ? a : 0.2f * a; }
__device__ __forceinline__ float bf2f(unsigned short u){ return __uint_as_float(((unsigned)u) << 16); }
__device__ __forceinline__ unsigned short f2bf(float f){
  __hip_bfloat16 h = __float2bfloat16(f);
  return *reinterpret_cast<unsigned short*>(&h);
}

// we = We @ a_edge (per layer), zero-padded to 64
__global__ void k_we(const float* __restrict__ We1, const float* __restrict__ ae1,
                     const float* __restrict__ We2, const float* __restrict__ ae2,
                     float* __restrict__ we1, float* __restrict__ we2, int ED, int H) {
  int j = threadIdx.x;  // 64 threads
  float s1 = 0.f, s2 = 0.f;
  if (j < ED) {
    const float4* r1 = reinterpret_cast<const float4*>(We1 + j * H);
    const float4* r2 = reinterpret_cast<const float4*>(We2 + j * H);
    const float4* a1 = reinterpret_cast<const float4*>(ae1);
    const float4* a2 = reinterpret_cast<const float4*>(ae2);
    for (int i = 0; i < H / 4; ++i) {
      float4 x1 = r1[i], y1 = a1[i];
      float4 x2 = r2[i], y2 = a2[i];
      s1 += x1.x*y1.x + x1.y*y1.y + x1.z*y1.z + x1.w*y1.w;
      s2 += x2.x*y2.x + x2.y*y2.y + x2.z*y2.z + x2.w*y2.w;
    }
  }
  we1[j] = s1; we2[j] = s2;
}

// W [K,128] fp32 -> Wt [128,K] bf16
__global__ void k_wt(const float* __restrict__ W, unsigned short* __restrict__ Wt, int K) {
  int idx = blockIdx.x * 256 + threadIdx.x;
  if (idx >= K * 128) return;
  int k = idx >> 7, n = idx & 127;
  Wt[(size_t)n * K + k] = f2bf(W[idx]);
}

__global__ void k_count(const int* __restrict__ dst, int* __restrict__ degi, int E) {
  int e = blockIdx.x * blockDim.x + threadIdx.x;
  if (e < E) atomicAdd(degi + dst[e], 1);
}

// single-block exclusive scan of degi -> rowptr
__global__ void k_scan(const int* __restrict__ degi, int* __restrict__ rowptr, int N, int E) {
  __shared__ int part[1024];
  int t = threadIdx.x;
  int chunk = (N + 1023) >> 10;
  int lo = t * chunk, hi = min(lo + chunk, N);
  int s = 0;
  for (int i = lo; i < hi; ++i) s += degi[i];
  part[t] = s;
  __syncthreads();
  for (int off = 1; off < 1024; off <<= 1) {
    int v = (t >= off) ? part[t - off] : 0;
    __syncthreads();
    part[t] += v;
    __syncthreads();
  }
  int base = (t == 0) ? 0 : part[t - 1];
  for (int i = lo; i < hi; ++i) { rowptr[i] = base; base += degi[i]; }
  if (t == 0) rowptr[N] = E;
}

// 4 lanes per edge: e-dots for both layers, single packed float4 CSR scatter
__global__ __launch_bounds__(256) void k_fill(const int* __restrict__ src, const int* __restrict__ dst,
                       const float* __restrict__ ef,
                       const float* __restrict__ we1, const float* __restrict__ we2,
                       const int* __restrict__ rowptr, int* __restrict__ cursor,
                       float4* __restrict__ csr, int E) {
  __shared__ float w1[64], w2[64];
  int t = threadIdx.x;
  if (t < 64) { w1[t] = we1[t]; w2[t] = we2[t]; }
  __syncthreads();
  int gid = blockIdx.x * 256 + t;
  int e = gid >> 2;
  int sub = gid & 3;
  if (e >= E) return;
  const float4* row = reinterpret_cast<const float4*>(ef + (size_t)e * 60);
  float d1 = 0.f, d2 = 0.f;
  #pragma unroll
  for (int i = sub; i < 15; i += 4) {
    float4 f = row[i];
    d1 += f.x*w1[4*i] + f.y*w1[4*i+1] + f.z*w1[4*i+2] + f.w*w1[4*i+3];
    d2 += f.x*w2[4*i] + f.y*w2[4*i+1] + f.z*w2[4*i+2] + f.w*w2[4*i+3];
  }
  d1 += __shfl_xor(d1, 1); d1 += __shfl_xor(d1, 2);
  d2 += __shfl_xor(d2, 1); d2 += __shfl_xor(d2, 2);
  if (sub == 0) {
    int d = dst[e];
    int slot = rowptr[d] + atomicAdd(cursor + d, 1);
    float4 v;
    v.x = __int_as_float(src[e]); v.y = d1; v.z = d2; v.w = 0.f;
    csr[slot] = v;
  }
}

// MFMA GEMM: C[M,128] = A[M,K] @ Bt[128,K]^T, bf16 MFMA, fp32 accum, bf16 out.
// One wave owns a 16x64 strip of C (4 accумulators).
template <int K, bool AFP32>
__global__ __launch_bounds__(256) void k_gemm(const void* __restrict__ Av, const unsigned short* __restrict__ Bt,
                                              unsigned short* __restrict__ C, int M) {
  int wid = (blockIdx.x * 256 + threadIdx.x) >> 6;
  int lane = threadIdx.x & 63;
  int mt = wid >> 1, hf = wid & 1;
  if (mt * 16 >= M) return;
  int r = lane & 15, quad = lane >> 4;
  int m = mt * 16 + r;
  floatx4 acc[4] = {};
  for (int k0 = 0; k0 < K; k0 += 32) {
    int kk = k0 + quad * 8;
    short8 a;
    if (AFP32) {
      const float4* ap = reinterpret_cast<const float4*>((const float*)Av + (size_t)m * K + kk);
      float4 lo = ap[0], hi = ap[1];
      union { short8 v; unsigned short u[8]; } pa;
      pa.u[0]=f2bf(lo.x); pa.u[1]=f2bf(lo.y); pa.u[2]=f2bf(lo.z); pa.u[3]=f2bf(lo.w);
      pa.u[4]=f2bf(hi.x); pa.u[5]=f2bf(hi.y); pa.u[6]=f2bf(hi.z); pa.u[7]=f2bf(hi.w);
      a = pa.v;
    } else {
      a = *reinterpret_cast<const short8*>((const unsigned short*)Av + (size_t)m * K + kk);
    }
    #pragma unroll
    for (int t = 0; t < 4; ++t) {
      short8 b = *reinterpret_cast<const short8*>(Bt + (size_t)(hf*64 + t*16 + r) * K + kk);
      acc[t] = __builtin_amdgcn_mfma_f32_16x16x32_bf16(a, b, acc[t], 0, 0, 0);
    }
  }
  #pragma unroll
  for (int t = 0; t < 4; ++t) {
    int col = hf * 64 + t * 16 + r;
    #pragma unroll
    for (int rr = 0; rr < 4; ++rr) {
      int row = mt * 16 + quad * 4 + rr;
      C[(size_t)row * 128 + col] = f2bf(acc[t][rr]);
    }
  }
}

// alpha_s[i] = h[i,:].a_src ; alpha_d[i] = h[i,:].a_dst  (one wave per node, h bf16)
__global__ void k_alpha(const unsigned short* __restrict__ h,
                        const float* __restrict__ a_src, const float* __restrict__ a_dst,
                        float* __restrict__ as_, float* __restrict__ ad_, int N) {
  int wave = (blockIdx.x * blockDim.x + threadIdx.x) >> 6;
  int lane = threadIdx.x & 63;
  if (wave >= N) return;
  unsigned u = *reinterpret_cast<const unsigned*>(h + (size_t)wave * 128 + lane * 2);
  float f0 = __uint_as_float(u << 16);
  float f1 = __uint_as_float(u & 0xffff0000u);
  float2 sv = reinterpret_cast<const float2*>(a_src)[lane];
  float2 dv = reinterpret_cast<const float2*>(a_dst)[lane];
  float ps = f0 * sv.x + f1 * sv.y;
  float pd = f0 * dv.x + f1 * dv.y;
  ps = wsum(ps);
  pd = wsum(pd);
  if (lane == 0) { as_[wave] = ps; ad_[wave] = pd; }
}

// single-pass online-softmax aggregation; wave per node, half-wave per edge stream,
// lane owns 4 channels; h gathered as bf16 (8 B/lane), out bf16.
__global__ __launch_bounds__(256) void k_agg(const int* __restrict__ rowptr, const float4* __restrict__ csr,
                      const float* __restrict__ as_, const float* __restrict__ ad_,
                      const unsigned short* __restrict__ h, const float* __restrict__ bias,
                      unsigned short* __restrict__ out, int N, int use2, int do_relu) {
  int i = (blockIdx.x * blockDim.x + threadIdx.x) >> 6;
  int lane = threadIdx.x & 63;
  if (i >= N) return;
  int q = lane & 31;
  int half = lane >> 5;
  int start = rowptr[i], end = rowptr[i + 1];
  int cnt = end - start;
  float adi = ad_[i], asi = as_[i];
  float m = -3.0e38f, s = 0.f, esum = 0.f;
  float4 acc = make_float4(0.f, 0.f, 0.f, 0.f);
  for (int idx = start + half; idx < end; idx += 2) {
    float4 ce = csr[idx];                       // broadcast within half-wave
    int sv = __float_as_int(ce.x);
    float e = use2 ? ce.z : ce.y;
    float a = lrelu(as_[sv] + adi + e);
    esum += e;
    if (a > m) {
      float r = __expf(m - a);                  // first hit: exp(-huge)=0
      s *= r; acc.x *= r; acc.y *= r; acc.z *= r; acc.w *= r;
      m = a;
    }
    float w = __expf(a - m);
    s += w;
    ushort4 hv = *reinterpret_cast<const ushort4*>(h + (size_t)sv * 128 + q * 4);
    acc.x += w * bf2f(hv.x); acc.y += w * bf2f(hv.y);
    acc.z += w * bf2f(hv.z); acc.w += w * bf2f(hv.w);
  }
  // merge halves
  float m_o = __shfl_xor(m, 32);
  float s_o = __shfl_xor(s, 32);
  float e_o = __shfl_xor(esum, 32);
  float4 ao;
  ao.x = __shfl_xor(acc.x, 32); ao.y = __shfl_xor(acc.y, 32);
  ao.z = __shfl_xor(acc.z, 32); ao.w = __shfl_xor(acc.w, 32);
  float Mn = fmaxf(m, m_o);
  float f  = __expf(m - Mn), fo = __expf(m_o - Mn);
  s = s * f + s_o * fo;
  acc.x = acc.x * f + ao.x * fo; acc.y = acc.y * f + ao.y * fo;
  acc.z = acc.z * f + ao.z * fo; acc.w = acc.w * f + ao.w * fo;
  float esum_t = esum + e_o;
  // merge self-loop
  float a_self = lrelu(asi + adi + esum_t / fmaxf((float)cnt, 1.f));
  float M2 = fmaxf(Mn, a_self);
  float g = __expf(Mn - M2);
  float w_self = __expf(a_self - M2);
  s = s * g + w_self;
  ushort4 hs = *reinterpret_cast<const ushort4*>(h + (size_t)i * 128 + q * 4);
  acc.x = acc.x * g + w_self * bf2f(hs.x); acc.y = acc.y * g + w_self * bf2f(hs.y);
  acc.z = acc.z * g + w_self * bf2f(hs.z); acc.w = acc.w * g + w_self * bf2f(hs.w);
  float inv = 1.0f / s;
  float4 bv = reinterpret_cast<const float4*>(bias)[q];
  float4 o;
  o.x = acc.x * inv + bv.x; o.y = acc.y * inv + bv.y;
  o.z = acc.z * inv + bv.z; o.w = acc.w * inv + bv.w;
  if (do_relu) {
    o.x = fmaxf(o.x, 0.f); o.y = fmaxf(o.y, 0.f);
    o.z = fmaxf(o.z, 0.f); o.w = fmaxf(o.w, 0.f);
  }
  if (half == 0) {
    ushort4 ov;
    ov.x = f2bf(o.x); ov.y = f2bf(o.y); ov.z = f2bf(o.z); ov.w = f2bf(o.w);
    *reinterpret_cast<ushort4*>(out + (size_t)i * 128 + q * 4) = ov;
  }
}

// out[k] = z[src[k]].z[dst[k]] + z[src[k+half]].z[dst[k+half]]; half-wave per pair, z bf16
__global__ void k_decode(const int* __restrict__ src, const int* __restrict__ dst,
                         const unsigned short* __restrict__ z, float* __restrict__ out, int halfE) {
  int k = (blockIdx.x * blockDim.x + threadIdx.x) >> 6;
  int lane = threadIdx.x & 63;
  if (k >= halfE) return;
  int hh = lane >> 5, q = lane & 31;
  int e = k + hh * halfE;
  int sv = src[e], dv = dst[e];               // broadcast within half-wave
  ushort4 a = *reinterpret_cast<const ushort4*>(z + (size_t)sv * 128 + q * 4);
  ushort4 b = *reinterpret_cast<const ushort4*>(z + (size_t)dv * 128 + q * 4);
  float p = bf2f(a.x)*bf2f(b.x) + bf2f(a.y)*bf2f(b.y)
          + bf2f(a.z)*bf2f(b.z) + bf2f(a.w)*bf2f(b.w);
  p = wsum(p);
  if (lane == 0) out[k] = p;
}

extern "C" void kernel_launch(void* const* d_in, const int* in_sizes, int n_in,
                              void* d_out, int out_size, void* d_ws, size_t ws_size,
                              hipStream_t stream) {
  const int H = 128;
  const int N = in_sizes[0] / 256;        // 50000
  const int E = in_sizes[1] / 2;          // 800000
  const int half = E / 2;

  const float* x   = (const float*)d_in[0];
  const int* eidx  = (const int*)d_in[1];
  const float* ef  = (const float*)d_in[2];
  const float* W1  = (const float*)d_in[4];
  const float* as1 = (const float*)d_in[5];
  const float* ad1 = (const float*)d_in[6];
  const float* We1 = (const float*)d_in[7];
  const float* ae1 = (const float*)d_in[8];
  const float* b1  = (const float*)d_in[9];
  const float* W2  = (const float*)d_in[10];
  const float* as2 = (const float*)d_in[11];
  const float* ad2 = (const float*)d_in[12];
  const float* We2 = (const float*)d_in[13];
  const float* ae2 = (const float*)d_in[14];
  const float* b2  = (const float*)d_in[15];

  const int* src = eidx;
  const int* dst = eidx + E;

  size_t off = 0;
  auto alloc = [&](size_t bytes) -> void* {
    void* p = (char*)d_ws + off;
    off += (bytes + 255) & ~(size_t)255;
    return p;
  };
  float*  we1    = (float*)alloc(64 * 4);
  float*  we2    = (float*)alloc(64 * 4);
  int*    degi   = (int*)alloc((size_t)N * 4);
  int*    cursor = (int*)alloc((size_t)N * 4);
  int*    rowptr = (int*)alloc((size_t)(N + 1) * 4);
  float*  alps   = (float*)alloc((size_t)N * 4);
  float*  alpd   = (float*)alloc((size_t)N * 4);
  float4* csr    = (float4*)alloc((size_t)E * 16);
  unsigned short* W1t = (unsigned short*)alloc((size_t)128 * 256 * 2);
  unsigned short* W2t = (unsigned short*)alloc((size_t)128 * 128 * 2);
  unsigned short* hA  = (unsigned short*)alloc((size_t)N * H * 2);
  unsigned short* hB  = (unsigned short*)alloc((size_t)N * H * 2);

  hipMemsetAsync(degi,   0, (size_t)N * 4, stream);
  hipMemsetAsync(cursor, 0, (size_t)N * 4, stream);

  k_we<<<1, 64, 0, stream>>>(We1, ae1, We2, ae2, we1, we2, 60, H);
  k_wt<<<(256 * 128 + 255) / 256, 256, 0, stream>>>(W1, W1t, 256);
  k_wt<<<(128 * 128 + 255) / 256, 256, 0, stream>>>(W2, W2t, 128);
  k_count<<<(E + 255) / 256, 256, 0, stream>>>(dst, degi, E);
  k_scan<<<1, 1024, 0, stream>>>(degi, rowptr, N, E);
  k_fill<<<(E * 4 + 255) / 256, 256, 0, stream>>>(src, dst, ef, we1, we2, rowptr, cursor, csr, E);

  int gwaves = ((N + 15) / 16) * 2;
  int gblocks = (gwaves + 3) / 4;
  // ---- layer 1 ----
  k_gemm<256, true><<<gblocks, 256, 0, stream>>>(x, W1t, hA, N);
  k_alpha<<<(N + 3) / 4, 256, 0, stream>>>(hA, as1, ad1, alps, alpd, N);
  k_agg<<<(N + 3) / 4, 256, 0, stream>>>(rowptr, csr, alps, alpd, hA, b1, hB, N, 0, 1);
  // ---- layer 2 ----
  k_gemm<128, false><<<gblocks, 256, 0, stream>>>(hB, W2t, hA, N);
  k_alpha<<<(N + 3) / 4, 256, 0, stream>>>(hA, as2, ad2, alps, alpd, N);
  k_agg<<<(N + 3) / 4, 256, 0, stream>>>(rowptr, csr, alps, alpd, hA, b2, hB, N, 1, 0);
  // ---- decode ----
  k_decode<<<(half + 3) / 4, 256, 0, stream>>>(src, dst, hB, (float*)d_out, half);
}

// Round 5
// 617.409 us; speedup vs baseline: 1.4137x; 1.2197x over previous
//
#include <hip/hip_runtime.h>
#include <hip/hip_bf16.h>

typedef __attribute__((ext_vector_type(8))) short short8;
typedef __attribute__((ext_vector_type(4))) float floatx4;

__device__ __forceinline__ float wsum(float v){
  #pragma unroll
  for (int m = 32; m >= 1; m >>= 1) v += __shfl_xor(v, m);
  return v;
}
__device__ __forceinline__ float lrelu(float a){ return a > 0.f ? a : 0.2f * a; }
__device__ __forceinline__ float bflo(unsigned u){ return __uint_as_float(u << 16); }
__device__ __forceinline__ float bfhi(unsigned u){ return __uint_as_float(u & 0xffff0000u); }
__device__ __forceinline__ unsigned short f2bf(float f){
  __hip_bfloat16 h = __float2bfloat16(f);
  return *reinterpret_cast<unsigned short*>(&h);
}

// fused: block 0 -> we1/we2 ; blocks 1..128 -> W1t ; blocks 129..192 -> W2t
__global__ __launch_bounds__(256) void k_prep(const float* __restrict__ We1, const float* __restrict__ ae1,
                       const float* __restrict__ We2, const float* __restrict__ ae2,
                       float* __restrict__ we1, float* __restrict__ we2,
                       const float* __restrict__ W1, unsigned short* __restrict__ W1t,
                       const float* __restrict__ W2, unsigned short* __restrict__ W2t) {
  int b = blockIdx.x, t = threadIdx.x;
  if (b == 0) {
    if (t >= 64) return;
    float s1 = 0.f, s2 = 0.f;
    if (t < 60) {
      const float4* r1 = reinterpret_cast<const float4*>(We1 + t * 128);
      const float4* r2 = reinterpret_cast<const float4*>(We2 + t * 128);
      const float4* a1 = reinterpret_cast<const float4*>(ae1);
      const float4* a2 = reinterpret_cast<const float4*>(ae2);
      for (int i = 0; i < 32; ++i) {
        float4 x1 = r1[i], y1 = a1[i];
        float4 x2 = r2[i], y2 = a2[i];
        s1 += x1.x*y1.x + x1.y*y1.y + x1.z*y1.z + x1.w*y1.w;
        s2 += x2.x*y2.x + x2.y*y2.y + x2.z*y2.z + x2.w*y2.w;
      }
    }
    we1[t] = s1; we2[t] = s2;
  } else if (b <= 128) {
    int idx = (b - 1) * 256 + t;            // K=256: 32768 elems
    int k = idx >> 7, n = idx & 127;
    W1t[(size_t)n * 256 + k] = f2bf(W1[idx]);
  } else {
    int idx = (b - 129) * 256 + t;          // K=128: 16384 elems
    int k = idx >> 7, n = idx & 127;
    W2t[(size_t)n * 128 + k] = f2bf(W2[idx]);
  }
}

// per-edge slot within its destination bucket + degree counts
__global__ void k_count(const int* __restrict__ dst, int* __restrict__ degi,
                        int* __restrict__ eslot, int E) {
  int e = blockIdx.x * blockDim.x + threadIdx.x;
  if (e < E) eslot[e] = atomicAdd(degi + dst[e], 1);
}

// single-block exclusive scan, int4 vectorized, fully unrolled (no dynamic reg indexing)
__global__ __launch_bounds__(1024) void k_scan(const int* __restrict__ degi, int* __restrict__ rowptr,
                                               int N, int E) {
  __shared__ int part[1024];
  int t = threadIdx.x;
  const int CH = 52;                 // 13 * int4 ; 1024*52 = 53248 >= N
  int lo = t * CH;
  int v[52];
  int s = 0;
  #pragma unroll
  for (int i = 0; i < 13; ++i) {
    int base_i = lo + 4 * i;
    if (base_i + 4 <= N) {
      int4 q = *reinterpret_cast<const int4*>(degi + base_i);
      v[4*i+0] = q.x; v[4*i+1] = q.y; v[4*i+2] = q.z; v[4*i+3] = q.w;
      s += q.x + q.y + q.z + q.w;
    } else {
      #pragma unroll
      for (int j = 0; j < 4; ++j) {
        int idx = base_i + j;
        int x = (idx < N) ? degi[idx] : 0;
        v[4*i+j] = x; s += x;
      }
    }
  }
  part[t] = s;
  __syncthreads();
  for (int off = 1; off < 1024; off <<= 1) {
    int u = (t >= off) ? part[t - off] : 0;
    __syncthreads();
    part[t] += u;
    __syncthreads();
  }
  int base = (t == 0) ? 0 : part[t - 1];
  #pragma unroll
  for (int i = 0; i < 13; ++i) {
    int base_i = lo + 4 * i;
    if (base_i + 4 <= N) {
      int4 o;
      o.x = base; base += v[4*i+0];
      o.y = base; base += v[4*i+1];
      o.z = base; base += v[4*i+2];
      o.w = base; base += v[4*i+3];
      *reinterpret_cast<int4*>(rowptr + base_i) = o;
    } else {
      #pragma unroll
      for (int j = 0; j < 4; ++j) {
        int idx = base_i + j;
        if (idx < N) { rowptr[idx] = base; base += v[4*i+j]; }
      }
    }
  }
  if (t == 0) rowptr[N] = E;
}

// 4 lanes per edge: e-dots for both layers, atomic-free packed float4 CSR scatter
__global__ __launch_bounds__(256) void k_fill(const int* __restrict__ src, const int* __restrict__ dst,
                       const float* __restrict__ ef,
                       const float* __restrict__ we1, const float* __restrict__ we2,
                       const int* __restrict__ rowptr, const int* __restrict__ eslot,
                       float4* __restrict__ csr, int E) {
  __shared__ float w1[64], w2[64];
  int t = threadIdx.x;
  if (t < 64) { w1[t] = we1[t]; w2[t] = we2[t]; }
  __syncthreads();
  int gid = blockIdx.x * 256 + t;
  int e = gid >> 2;
  int sub = gid & 3;
  if (e >= E) return;
  const float4* row = reinterpret_cast<const float4*>(ef + (size_t)e * 60);
  float d1 = 0.f, d2 = 0.f;
  #pragma unroll
  for (int i = sub; i < 15; i += 4) {
    float4 f = row[i];
    d1 += f.x*w1[4*i] + f.y*w1[4*i+1] + f.z*w1[4*i+2] + f.w*w1[4*i+3];
    d2 += f.x*w2[4*i] + f.y*w2[4*i+1] + f.z*w2[4*i+2] + f.w*w2[4*i+3];
  }
  d1 += __shfl_xor(d1, 1); d1 += __shfl_xor(d1, 2);
  d2 += __shfl_xor(d2, 1); d2 += __shfl_xor(d2, 2);
  if (sub == 0) {
    int d = dst[e];
    int slot = rowptr[d] + eslot[e];
    float4 v;
    v.x = __int_as_float(src[e]); v.y = d1; v.z = d2; v.w = 0.f;
    csr[slot] = v;
  }
}

// MFMA GEMM: C[M,128] = A[M,K] @ Bt[128,K]^T, bf16 MFMA, fp32 accum, bf16 out.
template <int K, bool AFP32>
__global__ __launch_bounds__(256) void k_gemm(const void* __restrict__ Av, const unsigned short* __restrict__ Bt,
                                              unsigned short* __restrict__ C, int M) {
  int wid = (blockIdx.x * 256 + threadIdx.x) >> 6;
  int lane = threadIdx.x & 63;
  int mt = wid >> 1, hf = wid & 1;
  if (mt * 16 >= M) return;
  int r = lane & 15, quad = lane >> 4;
  int m = mt * 16 + r;
  floatx4 acc[4] = {};
  for (int k0 = 0; k0 < K; k0 += 32) {
    int kk = k0 + quad * 8;
    short8 a;
    if (AFP32) {
      const float4* ap = reinterpret_cast<const float4*>((const float*)Av + (size_t)m * K + kk);
      float4 lo = ap[0], hi = ap[1];
      union { short8 v; unsigned short u[8]; } pa;
      pa.u[0]=f2bf(lo.x); pa.u[1]=f2bf(lo.y); pa.u[2]=f2bf(lo.z); pa.u[3]=f2bf(lo.w);
      pa.u[4]=f2bf(hi.x); pa.u[5]=f2bf(hi.y); pa.u[6]=f2bf(hi.z); pa.u[7]=f2bf(hi.w);
      a = pa.v;
    } else {
      a = *reinterpret_cast<const short8*>((const unsigned short*)Av + (size_t)m * K + kk);
    }
    #pragma unroll
    for (int t = 0; t < 4; ++t) {
      short8 b = *reinterpret_cast<const short8*>(Bt + (size_t)(hf*64 + t*16 + r) * K + kk);
      acc[t] = __builtin_amdgcn_mfma_f32_16x16x32_bf16(a, b, acc[t], 0, 0, 0);
    }
  }
  #pragma unroll
  for (int t = 0; t < 4; ++t) {
    int col = hf * 64 + t * 16 + r;
    #pragma unroll
    for (int rr = 0; rr < 4; ++rr) {
      int row = mt * 16 + quad * 4 + rr;
      C[(size_t)row * 128 + col] = f2bf(acc[t][rr]);
    }
  }
}

// alpha_s[i] = h[i,:].a_src ; alpha_d[i] = h[i,:].a_dst  (one wave per node, h bf16)
__global__ void k_alpha(const unsigned short* __restrict__ h,
                        const float* __restrict__ a_src, const float* __restrict__ a_dst,
                        float* __restrict__ as_, float* __restrict__ ad_, int N) {
  int wave = (blockIdx.x * blockDim.x + threadIdx.x) >> 6;
  int lane = threadIdx.x & 63;
  if (wave >= N) return;
  unsigned u = *reinterpret_cast<const unsigned*>(h + (size_t)wave * 128 + lane * 2);
  float f0 = bflo(u), f1 = bfhi(u);
  float2 sv = reinterpret_cast<const float2*>(a_src)[lane];
  float2 dv = reinterpret_cast<const float2*>(a_dst)[lane];
  float ps = f0 * sv.x + f1 * sv.y;
  float pd = f0 * dv.x + f1 * dv.y;
  ps = wsum(ps);
  pd = wsum(pd);
  if (lane == 0) { as_[wave] = ps; ad_[wave] = pd; }
}

// online-softmax aggregation; wave per node, 4 edge streams (quarter-wave each),
// lane owns 8 channels (uint4 = 8 bf16); csr record double-buffered in registers.
__global__ __launch_bounds__(256) void k_agg(const int* __restrict__ rowptr, const float4* __restrict__ csr,
                      const float* __restrict__ as_, const float* __restrict__ ad_,
                      const unsigned short* __restrict__ h, const float* __restrict__ bias,
                      unsigned short* __restrict__ out, int N, int use2, int do_relu) {
  int i = (blockIdx.x * blockDim.x + threadIdx.x) >> 6;
  int lane = threadIdx.x & 63;
  if (i >= N) return;
  int st = lane >> 4;       // stream 0..3
  int q  = lane & 15;       // channel group: ch [8q, 8q+8)
  int start = rowptr[i], end = rowptr[i + 1];
  int cnt = end - start;
  float adi = ad_[i], asi = as_[i];
  float m = -3.0e38f, s = 0.f, esum = 0.f;
  float acc[8] = {};
  int idx = start + st;
  float4 cur;
  if (idx < end) cur = csr[idx];
  for (; idx < end; idx += 4) {
    int nidx = idx + 4;
    float4 nxt;
    if (nidx < end) nxt = csr[nidx];
    int sv = __float_as_int(cur.x);
    float e = use2 ? cur.z : cur.y;
    float a = lrelu(as_[sv] + adi + e);
    esum += e;
    if (a > m) {
      float r = __expf(m - a);
      s *= r;
      #pragma unroll
      for (int j = 0; j < 8; ++j) acc[j] *= r;
      m = a;
    }
    float w = __expf(a - m);
    s += w;
    uint4 hv = *reinterpret_cast<const uint4*>(h + (size_t)sv * 128 + q * 8);
    acc[0] += w * bflo(hv.x); acc[1] += w * bfhi(hv.x);
    acc[2] += w * bflo(hv.y); acc[3] += w * bfhi(hv.y);
    acc[4] += w * bflo(hv.z); acc[5] += w * bfhi(hv.z);
    acc[6] += w * bflo(hv.w); acc[7] += w * bfhi(hv.w);
    cur = nxt;
  }
  // merge 4 streams: xor 16 then xor 32
  #pragma unroll
  for (int off = 16; off <= 32; off <<= 1) {
    float m_o = __shfl_xor(m, off);
    float s_o = __shfl_xor(s, off);
    float e_o = __shfl_xor(esum, off);
    float ao[8];
    #pragma unroll
    for (int j = 0; j < 8; ++j) ao[j] = __shfl_xor(acc[j], off);
    float Mn = fmaxf(m, m_o);
    float f  = __expf(m - Mn), fo = __expf(m_o - Mn);
    s = s * f + s_o * fo;
    #pragma unroll
    for (int j = 0; j < 8; ++j) acc[j] = acc[j] * f + ao[j] * fo;
    esum += e_o;
    m = Mn;
  }
  // merge self-loop
  float a_self = lrelu(asi + adi + esum / fmaxf((float)cnt, 1.f));
  float M2 = fmaxf(m, a_self);
  float g = __expf(m - M2);
  float w_self = __expf(a_self - M2);
  s = s * g + w_self;
  uint4 hs = *reinterpret_cast<const uint4*>(h + (size_t)i * 128 + q * 8);
  float hsf[8] = { bflo(hs.x), bfhi(hs.x), bflo(hs.y), bfhi(hs.y),
                   bflo(hs.z), bfhi(hs.z), bflo(hs.w), bfhi(hs.w) };
  #pragma unroll
  for (int j = 0; j < 8; ++j) acc[j] = acc[j] * g + w_self * hsf[j];
  float inv = 1.0f / s;
  float4 bv0 = *reinterpret_cast<const float4*>(bias + q * 8);
  float4 bv1 = *reinterpret_cast<const float4*>(bias + q * 8 + 4);
  float o[8];
  o[0] = acc[0]*inv + bv0.x; o[1] = acc[1]*inv + bv0.y;
  o[2] = acc[2]*inv + bv0.z; o[3] = acc[3]*inv + bv0.w;
  o[4] = acc[4]*inv + bv1.x; o[5] = acc[5]*inv + bv1.y;
  o[6] = acc[6]*inv + bv1.z; o[7] = acc[7]*inv + bv1.w;
  if (do_relu) {
    #pragma unroll
    for (int j = 0; j < 8; ++j) o[j] = fmaxf(o[j], 0.f);
  }
  if (st == 0) {
    uint4 ov;
    ov.x = (unsigned)f2bf(o[0]) | ((unsigned)f2bf(o[1]) << 16);
    ov.y = (unsigned)f2bf(o[2]) | ((unsigned)f2bf(o[3]) << 16);
    ov.z = (unsigned)f2bf(o[4]) | ((unsigned)f2bf(o[5]) << 16);
    ov.w = (unsigned)f2bf(o[6]) | ((unsigned)f2bf(o[7]) << 16);
    *reinterpret_cast<uint4*>(out + (size_t)i * 128 + q * 8) = ov;
  }
}

// decode: wave handles 4 consecutive k; half-wave per e, lane owns 4 channels (8 B)
__global__ void k_decode(const int* __restrict__ src, const int* __restrict__ dst,
                         const unsigned short* __restrict__ z, float* __restrict__ out, int halfE) {
  int w = (blockIdx.x * blockDim.x + threadIdx.x) >> 6;
  int lane = threadIdx.x & 63;
  int k0 = w * 4;
  if (k0 >= halfE) return;
  int hh = lane >> 5, q = lane & 31;
  float p[4];
  #pragma unroll
  for (int r = 0; r < 4; ++r) {
    p[r] = 0.f;
    int k = k0 + r;
    if (k < halfE) {
      int e = k + hh * halfE;
      int sv = src[e], dv = dst[e];
      uint2 a = *reinterpret_cast<const uint2*>(z + (size_t)sv * 128 + q * 4);
      uint2 b = *reinterpret_cast<const uint2*>(z + (size_t)dv * 128 + q * 4);
      p[r] = bflo(a.x)*bflo(b.x) + bfhi(a.x)*bfhi(b.x)
           + bflo(a.y)*bflo(b.y) + bfhi(a.y)*bfhi(b.y);
    }
  }
  #pragma unroll
  for (int r = 0; r < 4; ++r) p[r] = wsum(p[r]);
  if (lane == 0) {
    if (k0 + 4 <= halfE) {
      float4 ov = make_float4(p[0], p[1], p[2], p[3]);
      *reinterpret_cast<float4*>(out + k0) = ov;
    } else {
      for (int r = 0; r < 4 && k0 + r < halfE; ++r) out[k0 + r] = p[r];
    }
  }
}

extern "C" void kernel_launch(void* const* d_in, const int* in_sizes, int n_in,
                              void* d_out, int out_size, void* d_ws, size_t ws_size,
                              hipStream_t stream) {
  const int H = 128;
  const int N = in_sizes[0] / 256;        // 50000
  const int E = in_sizes[1] / 2;          // 800000
  const int half = E / 2;

  const float* x   = (const float*)d_in[0];
  const int* eidx  = (const int*)d_in[1];
  const float* ef  = (const float*)d_in[2];
  const float* W1  = (const float*)d_in[4];
  const float* as1 = (const float*)d_in[5];
  const float* ad1 = (const float*)d_in[6];
  const float* We1 = (const float*)d_in[7];
  const float* ae1 = (const float*)d_in[8];
  const float* b1  = (const float*)d_in[9];
  const float* W2  = (const float*)d_in[10];
  const float* as2 = (const float*)d_in[11];
  const float* ad2 = (const float*)d_in[12];
  const float* We2 = (const float*)d_in[13];
  const float* ae2 = (const float*)d_in[14];
  const float* b2  = (const float*)d_in[15];

  const int* src = eidx;
  const int* dst = eidx + E;

  size_t off = 0;
  auto alloc = [&](size_t bytes) -> void* {
    void* p = (char*)d_ws + off;
    off += (bytes + 255) & ~(size_t)255;
    return p;
  };
  float*  we1    = (float*)alloc(64 * 4);
  float*  we2    = (float*)alloc(64 * 4);
  int*    degi   = (int*)alloc((size_t)N * 4);
  int*    eslot  = (int*)alloc((size_t)E * 4);
  int*    rowptr = (int*)alloc((size_t)(N + 1) * 4);
  float*  alps   = (float*)alloc((size_t)N * 4);
  float*  alpd   = (float*)alloc((size_t)N * 4);
  float4* csr    = (float4*)alloc((size_t)E * 16);
  unsigned short* W1t = (unsigned short*)alloc((size_t)128 * 256 * 2);
  unsigned short* W2t = (unsigned short*)alloc((size_t)128 * 128 * 2);
  unsigned short* hA  = (unsigned short*)alloc((size_t)N * H * 2);
  unsigned short* hB  = (unsigned short*)alloc((size_t)N * H * 2);

  hipMemsetAsync(degi, 0, (size_t)N * 4, stream);

  k_prep<<<193, 256, 0, stream>>>(We1, ae1, We2, ae2, we1, we2, W1, W1t, W2, W2t);
  k_count<<<(E + 255) / 256, 256, 0, stream>>>(dst, degi, eslot, E);
  k_scan<<<1, 1024, 0, stream>>>(degi, rowptr, N, E);
  k_fill<<<(E * 4 + 255) / 256, 256, 0, stream>>>(src, dst, ef, we1, we2, rowptr, eslot, csr, E);

  int gwaves = ((N + 15) / 16) * 2;
  int gblocks = (gwaves + 3) / 4;
  // ---- layer 1 ----
  k_gemm<256, true><<<gblocks, 256, 0, stream>>>(x, W1t, hA, N);
  k_alpha<<<(N + 3) / 4, 256, 0, stream>>>(hA, as1, ad1, alps, alpd, N);
  k_agg<<<(N + 3) / 4, 256, 0, stream>>>(rowptr, csr, alps, alpd, hA, b1, hB, N, 0, 1);
  // ---- layer 2 ----
  k_gemm<128, false><<<gblocks, 256, 0, stream>>>(hB, W2t, hA, N);
  k_alpha<<<(N + 3) / 4, 256, 0, stream>>>(hA, as2, ad2, alps, alpd, N);
  k_agg<<<(N + 3) / 4, 256, 0, stream>>>(rowptr, csr, alps, alpd, hA, b2, hB, N, 1, 0);
  // ---- decode ----
  int dwaves = (half + 3) / 4;
  k_decode<<<(dwaves + 3) / 4, 256, 0, stream>>>(src, dst, hB, (float*)d_out, half);
}